// Round 3
// baseline (751.993 us; speedup 1.0000x reference)
//
#include <hip/hip_runtime.h>
#include <hip/hip_bf16.h>
#include <math.h>

#define HEADS 8
#define DIMH 40
#define BB 8
#define NN 4096
#define JJ 77
#define QD 320
#define CDIM 768
#define INNER 320
#define NEGF (-3.4028234663852886e38f)

using bf16 = __hip_bfloat16;

__device__ __forceinline__ float b2f(bf16 v){ return __bfloat162float(v); }
__device__ __forceinline__ bf16 f2b(float f){ return __float2bfloat16(f); }
__device__ __forceinline__ unsigned short f2u(float f){
    bf16 t = __float2bfloat16(f);
    return *reinterpret_cast<unsigned short*>(&t);
}
// flag-branched float load: isf32 ? fp32 : bf16
__device__ __forceinline__ float ldf(const void* p, size_t i, int isf32){
    if(isf32) return ((const float*)p)[i];
    return b2f(((const bf16*)p)[i]);
}

struct Stats { double s1; double s2; int validcnt; int gflag; int isf32; float simstd; };

// ---------------- prep: zero stats, detect dtypes, count valid keys
__global__ void prep_kernel(const unsigned int* xw, const int* ct, const int* gpm, Stats* st){
    __shared__ int sflag, scnt, ssane;
    if(threadIdx.x==0){ sflag=0; scnt=0; ssane=0; }
    __syncthreads();
    int lflag=0, lcnt=0, lsane=0;
    // gpm width scan: only first 616 bytes (=154 words) — safe under either layout
    for(int i=threadIdx.x;i<154;i+=blockDim.x){
        int g = gpm[i];
        if(g!=0 && g!=1) lflag=1;
    }
    for(int i=threadIdx.x;i<BB*JJ;i+=blockDim.x){
        if(ct[i]>=0) lcnt++;
    }
    // x dtype scan: low 16 bits of each word as bf16 — sane exponent => true bf16 data
    for(int i=threadIdx.x;i<1024;i+=blockDim.x){
        unsigned int u = xw[i] & 0xFFFFu;
        int e = (int)((u>>7)&0xFFu);
        if((e>=100 && e<=140) || u==0u || u==0x8000u) lsane++;
    }
    if(lflag) atomicOr(&sflag,1);
    atomicAdd(&scnt,lcnt);
    atomicAdd(&ssane,lsane);
    __syncthreads();
    if(threadIdx.x==0){
        st->s1=0.0; st->s2=0.0; st->validcnt=scnt; st->gflag=sflag;
        st->isf32 = (ssane < 512) ? 1 : 0;
    }
}

// ---------------- k,v projection: one block per (b,j) row
__global__ __launch_bounds__(256) void proj_kv(const void* embs, const void* Wk, const void* Wv,
                                               float* kws, float* vws, const Stats* st){
    int isf32 = st->isf32;
    int bj = blockIdx.x; int b = bj / JJ; int j = bj % JJ;
    __shared__ float e[CDIM];
    for(int i=threadIdx.x;i<CDIM;i+=blockDim.x) e[i]=ldf(embs,(size_t)bj*CDIM+i,isf32);
    __syncthreads();
    for(int i=threadIdx.x;i<2*INNER;i+=blockDim.x){
        int col = (i<INNER)? i : i-INNER;
        const void* W = (i<INNER)? Wk : Wv;
        float acc=0.f;
        for(int c=0;c<CDIM;c++) acc += e[c]*ldf(W,(size_t)c*INNER+col,isf32);
        int h = col/DIMH, d = col%DIMH;
        float* dst = (i<INNER)? kws : vws;
        dst[(((size_t)b*HEADS+h)*JJ + j)*DIMH + d] = acc;
    }
}

// ---------------- tiled GEMM: C[M][320] = A[M][320] * W[320][320] (+bias)
// afollow/cfollow: 1 => dtype follows st->isf32, 0 => forced bf16
template<bool BIAS>
__global__ __launch_bounds__(256) void gemm320(const void* __restrict__ A,
                                               const void* __restrict__ Wmat,
                                               const void* __restrict__ bias,
                                               void* __restrict__ C,
                                               const Stats* st, int afollow, int cfollow){
    int isf32 = st->isf32;
    int a_f32 = afollow ? isf32 : 0;
    int c_f32 = cfollow ? isf32 : 0;
    __shared__ float As[16][64];
    __shared__ float Bs[16][64];
    int t = threadIdx.x;
    int bm = blockIdx.x & 511;        // M/64 = 512
    int bn = blockIdx.x >> 9;         // 0..4
    int tm = t>>4, tn = t&15;
    int row0 = bm*64, col0 = bn*64;
    float acc[4][4];
    #pragma unroll
    for(int i=0;i<4;i++)
        #pragma unroll
        for(int j=0;j<4;j++) acc[i][j]=0.f;

    for(int k0=0;k0<320;k0+=16){
        #pragma unroll
        for(int i=0;i<4;i++){
            int li = t + i*256;
            int m = li>>4, kk = li&15;
            As[kk][m] = ldf(A,(size_t)(row0+m)*320 + k0+kk, a_f32);
        }
        #pragma unroll
        for(int i=0;i<4;i++){
            int li = t + i*256;
            int kk = li>>6, nn = li&63;
            Bs[kk][nn] = ldf(Wmat,(size_t)(k0+kk)*320 + col0+nn, isf32);
        }
        __syncthreads();
        #pragma unroll
        for(int kk=0;kk<16;kk++){
            float4 a4 = *(const float4*)&As[kk][tm*4];
            float4 b4 = *(const float4*)&Bs[kk][tn*4];
            float av[4]={a4.x,a4.y,a4.z,a4.w};
            float bv[4]={b4.x,b4.y,b4.z,b4.w};
            #pragma unroll
            for(int i=0;i<4;i++)
                #pragma unroll
                for(int j=0;j<4;j++) acc[i][j] += av[i]*bv[j];
        }
        __syncthreads();
    }
    #pragma unroll
    for(int i=0;i<4;i++){
        int r = row0 + tm*4 + i;
        int c = col0 + tn*4;
        float v0 = acc[i][0], v1 = acc[i][1], v2 = acc[i][2], v3 = acc[i][3];
        if(BIAS){
            v0 += ldf(bias,c+0,isf32); v1 += ldf(bias,c+1,isf32);
            v2 += ldf(bias,c+2,isf32); v3 += ldf(bias,c+3,isf32);
        }
        if(c_f32){
            float4 f4; f4.x=v0; f4.y=v1; f4.z=v2; f4.w=v3;
            *(float4*)&((float*)C)[(size_t)r*320 + c] = f4;
        }else{
            ushort4 pack;
            pack.x = f2u(v0); pack.y = f2u(v1);
            pack.z = f2u(v2); pack.w = f2u(v3);
            *(ushort4*)&((bf16*)C)[(size_t)r*320 + c] = pack;
        }
    }
}

// ---------------- global masked moments of sim (qws is always bf16)
__global__ __launch_bounds__(256) void stats_kernel(const bf16* __restrict__ qws,
                                                    const float* __restrict__ kws,
                                                    const int* __restrict__ ct, Stats* st){
    int bh = blockIdx.x;             // 0..63
    int n0 = blockIdx.y*256;
    int b  = bh>>3, h = bh&7;
    __shared__ float kl[JJ*DIMH];
    __shared__ int kvalid[JJ];
    for(int i=threadIdx.x;i<JJ*DIMH;i+=256) kl[i]=kws[(size_t)bh*JJ*DIMH+i];
    if(threadIdx.x<JJ) kvalid[threadIdx.x] = (ct[b*JJ+threadIdx.x]>=0)?1:0;
    __syncthreads();
    int n = n0 + threadIdx.x;
    const bf16* qr = qws + (size_t)(b*NN+n)*INNER + h*DIMH;
    float q[DIMH];
    #pragma unroll
    for(int d=0;d<DIMH;d++) q[d]=b2f(qr[d]);
    float s1=0.f, s2=0.f;
    for(int j=0;j<JJ;j++){
        float s=0.f;
        #pragma unroll
        for(int d=0;d<DIMH;d++) s += q[d]*kl[j*DIMH+d];
        if(kvalid[j]){ s1+=s; s2+=s*s; }
    }
    #pragma unroll
    for(int off=32;off>0;off>>=1){ s1 += __shfl_down(s1,off); s2 += __shfl_down(s2,off); }
    __shared__ float sa[4], sb[4];
    int lane = threadIdx.x&63, w = threadIdx.x>>6;
    if(lane==0){ sa[w]=s1; sb[w]=s2; }
    __syncthreads();
    if(threadIdx.x==0){
        double S1 = (double)sa[0]+sa[1]+sa[2]+sa[3];
        double S2 = (double)sb[0]+sb[1]+sb[2]+sb[3];
        atomicAdd(&st->s1, S1);
        atomicAdd(&st->s2, S2);
    }
}

__global__ void finalize_kernel(Stats* st){
    double cnt = (double)st->validcnt * HEADS * NN;
    double var = (st->s2 - st->s1*st->s1/cnt)/(cnt-1.0);
    st->simstd = (float)sqrt(var);
}

// ---------------- fused attention: recompute sim, mask+wf, softmax, PV
__global__ __launch_bounds__(256) void attn_kernel(const bf16* __restrict__ qws,
                                                   const float* __restrict__ kws,
                                                   const float* __restrict__ vws,
                                                   const void* __restrict__ cam,
                                                   const void* __restrict__ strength,
                                                   const int* __restrict__ ct,
                                                   const int* __restrict__ gpm,
                                                   const Stats* st,
                                                   bf16* __restrict__ ao){
    int isf32 = st->isf32;
    int bh = blockIdx.x; int n0 = blockIdx.y*256;
    int b = bh>>3, h = bh&7;
    __shared__ float kl[JJ*DIMH], vl[JJ*DIMH];
    __shared__ float kmul[JJ], addj[JJ], gmulc[JJ];
    for(int i=threadIdx.x;i<JJ*DIMH;i+=256){
        kl[i]=kws[(size_t)bh*JJ*DIMH+i];
        vl[i]=vws[(size_t)bh*JJ*DIMH+i];
    }
    if(threadIdx.x<JJ){
        int j=threadIdx.x;
        int kv = ct[b*JJ+j]>=0;
        int gv;
        if(st->gflag) gv = (((const unsigned char*)gpm)[b*JJ+j]!=0);
        else          gv = (gpm[b*JJ+j]!=0);
        float c = st->simstd * ldf(strength,0,isf32);
        kmul[j] = kv?1.f:0.f;
        addj[j] = (kv?0.f:NEGF) + (gv?0.f:NEGF);
        gmulc[j]= gv? c : 0.f;
    }
    __syncthreads();
    int n = n0+threadIdx.x;
    const bf16* qr = qws + (size_t)(b*NN+n)*INNER + h*DIMH;
    float q[DIMH];
    #pragma unroll
    for(int d=0;d<DIMH;d++) q[d]=b2f(qr[d]);
    size_t cambase = (size_t)(b*NN+n)*JJ;
    const float scale = 0.15811388300841897f;
    float m = -INFINITY;
    float camv[JJ];
    for(int j=0;j<JJ;j++) camv[j] = ldf(cam,cambase+j,isf32);
    for(int j=0;j<JJ;j++){
        float s=0.f;
        #pragma unroll
        for(int d=0;d<DIMH;d++) s += q[d]*kl[j*DIMH+d];
        float logit = (s*kmul[j] + camv[j]*gmulc[j] + addj[j])*scale;
        m = fmaxf(m, logit);
    }
    float denom=0.f;
    float o[DIMH];
    #pragma unroll
    for(int d=0;d<DIMH;d++) o[d]=0.f;
    for(int j=0;j<JJ;j++){
        float s=0.f;
        #pragma unroll
        for(int d=0;d<DIMH;d++) s += q[d]*kl[j*DIMH+d];
        float logit = (s*kmul[j] + camv[j]*gmulc[j] + addj[j])*scale;
        float p = __expf(logit - m);
        denom += p;
        #pragma unroll
        for(int d=0;d<DIMH;d++) o[d] += p*vl[j*DIMH+d];
    }
    float inv = 1.f/denom;
    bf16* aor = ao + (size_t)(b*NN+n)*INNER + h*DIMH;
    #pragma unroll
    for(int d=0;d<DIMH;d++) aor[d] = f2b(o[d]*inv);
}

extern "C" void kernel_launch(void* const* d_in, const int* in_sizes, int n_in,
                              void* d_out, int out_size, void* d_ws, size_t ws_size,
                              hipStream_t stream) {
    const void* x        = d_in[0];
    const void* embs     = d_in[1];
    const void* Wq       = d_in[2];
    const void* Wk       = d_in[3];
    const void* Wv       = d_in[4];
    const void* Wo       = d_in[5];
    const void* bo       = d_in[6];
    const void* cam      = d_in[7];
    const void* strength = d_in[8];
    const int*  ct       = (const int*)d_in[9];
    const int*  gpm      = (const int*)d_in[10];

    char* ws = (char*)d_ws;
    bf16*  qws = (bf16*)ws;                       // 20,971,520 B
    bf16*  ao  = (bf16*)(ws + 20971520);          // 20,971,520 B
    float* kws = (float*)(ws + 41943040);         // 788,480 B
    float* vws = (float*)(ws + 42731520);         // 788,480 B
    Stats* st  = (Stats*)(ws + 43520000);

    prep_kernel<<<1,256,0,stream>>>((const unsigned int*)x,ct,gpm,st);
    proj_kv<<<BB*JJ,256,0,stream>>>(embs,Wk,Wv,kws,vws,st);
    gemm320<false><<<2560,256,0,stream>>>(x,Wq,nullptr,qws,st,1,0);
    stats_kernel<<<dim3(64,16),256,0,stream>>>(qws,kws,ct,st);
    finalize_kernel<<<1,1,0,stream>>>(st);
    attn_kernel<<<dim3(64,16),256,0,stream>>>(qws,kws,vws,cam,strength,ct,gpm,st,ao);
    gemm320<true><<<2560,256,0,stream>>>(ao,Wo,bo,d_out,st,0,1);
}

// Round 4
// 332.866 us; speedup vs baseline: 2.2591x; 2.2591x over previous
//
#include <hip/hip_runtime.h>
#include <hip/hip_bf16.h>
#include <math.h>

#define HEADS 8
#define DIMH 40
#define BB 8
#define NN 4096
#define JJ 77
#define CDIM 768
#define INNER 320
#define NEGF (-3.4028234663852886e38f)

using bf16 = __hip_bfloat16;
using f32x4 = __attribute__((ext_vector_type(4))) float;
using bf16x8 = __attribute__((ext_vector_type(8))) short;
using ushort8 = __attribute__((ext_vector_type(8))) unsigned short;
using ushort4v = __attribute__((ext_vector_type(4))) unsigned short;

__device__ __forceinline__ unsigned short f2u(float f){
    bf16 t = __float2bfloat16(f);
    return *reinterpret_cast<unsigned short*>(&t);
}
__device__ __forceinline__ float u2f(unsigned short u){
    unsigned int w = ((unsigned int)u) << 16;
    return __uint_as_float(w);
}

struct Stats { double s1; double s2; int validcnt; int gflag; float simstd; };

// ---------------- prep: zero stats, detect gpm storage width, count valid keys
__global__ void prep_kernel(const int* ct, const int* gpm, Stats* st){
    __shared__ int sflag, scnt;
    if(threadIdx.x==0){ sflag=0; scnt=0; }
    __syncthreads();
    int lflag=0, lcnt=0;
    for(int i=threadIdx.x;i<154;i+=blockDim.x){
        int g = gpm[i];
        if(g!=0 && g!=1) lflag=1;
    }
    for(int i=threadIdx.x;i<BB*JJ;i+=blockDim.x){
        if(ct[i]>=0) lcnt++;
    }
    if(lflag) atomicOr(&sflag,1);
    atomicAdd(&scnt,lcnt);
    __syncthreads();
    if(threadIdx.x==0){ st->s1=0.0; st->s2=0.0; st->validcnt=scnt; st->gflag=sflag; }
}

// ---------------- transpose + fp32->bf16: out[C][R] = in[R][C]
__global__ __launch_bounds__(256) void transpose_conv(const float* __restrict__ in,
                                                      unsigned short* __restrict__ out,
                                                      int R, int C){
    __shared__ float tile[32][33];
    int nbx = C/32;
    int bx = blockIdx.x % nbx, by = blockIdx.x / nbx;
    int c0 = bx*32, r0 = by*32;
    int tx = threadIdx.x & 31, ty = threadIdx.x >> 5;   // 8 rows/pass
    #pragma unroll
    for(int i=0;i<32;i+=8) tile[ty+i][tx] = in[(size_t)(r0+ty+i)*C + c0+tx];
    __syncthreads();
    #pragma unroll
    for(int i=0;i<32;i+=8) out[(size_t)(c0+ty+i)*R + r0+tx] = f2u(tile[tx][ty+i]);
}

// ---------------- k,v projection: one block per (b,j) row -> bf16 [bh][j][40]
__global__ __launch_bounds__(256) void proj_kv(const float* __restrict__ embs,
                                               const float* __restrict__ Wk,
                                               const float* __restrict__ Wv,
                                               unsigned short* kws, unsigned short* vws){
    int bj = blockIdx.x; int b = bj / JJ; int j = bj % JJ;
    __shared__ float e[CDIM];
    const float* er = embs + (size_t)bj*CDIM;
    for(int i=threadIdx.x;i<CDIM;i+=blockDim.x) e[i]=er[i];
    __syncthreads();
    for(int i=threadIdx.x;i<2*INNER;i+=blockDim.x){
        int col = (i<INNER)? i : i-INNER;
        const float* W = (i<INNER)? Wk : Wv;
        float acc=0.f;
        for(int c=0;c<CDIM;c++) acc += e[c]*W[(size_t)c*INNER+col];
        int h = col/DIMH, d = col%DIMH;
        unsigned short* dst = (i<INNER)? kws : vws;
        dst[(((size_t)b*HEADS+h)*JJ + j)*DIMH + d] = f2u(acc);
    }
}

// ---------------- MFMA GEMM: C[M][320] = A[M][320] * B[320][320] (+bias)
// Bt: bf16, pre-transposed [n][k]. A: fp32 (A_BF16=0) or bf16 (A_BF16=1).
// C: bf16 (C_F32=0) or fp32+bias (C_F32=1).
template<int A_BF16, int C_F32>
__global__ __launch_bounds__(256) void gemm_mfma(const void* __restrict__ A,
                                                 const unsigned short* __restrict__ Bt,
                                                 const float* __restrict__ bias,
                                                 void* __restrict__ C){
    __shared__ unsigned short As[128][40];   // 80 B rows: 16B-aligned, ~2-way banks
    __shared__ unsigned short Bs[64][40];
    int t = threadIdx.x;
    int bm = blockIdx.x & 255;               // 32768/128 = 256
    int bn = blockIdx.x >> 8;                // 0..4
    int row0 = bm*128, col0 = bn*64;
    int wave = t>>6, lane = t&63;
    int wm = wave>>1, wn = wave&1;
    int l15 = lane&15, lk = lane>>4;

    f32x4 acc[4][2];
    #pragma unroll
    for(int i=0;i<4;i++)
        #pragma unroll
        for(int j=0;j<2;j++) acc[i][j] = (f32x4){0.f,0.f,0.f,0.f};

    for(int k0=0;k0<320;k0+=32){
        if(A_BF16){
            const unsigned short* Ab = (const unsigned short*)A;
            #pragma unroll
            for(int p=0;p<2;p++){
                int li = (p*256+t)*8; int r = li>>5, kk = li&31;
                *(ushort8*)&As[r][kk] = *(const ushort8*)&Ab[(size_t)(row0+r)*320 + k0+kk];
            }
        } else {
            const float* Af = (const float*)A;
            #pragma unroll
            for(int p=0;p<4;p++){
                int li = (p*256+t)*4; int r = li>>5, kk = li&31;
                float4 v = *(const float4*)&Af[(size_t)(row0+r)*320 + k0+kk];
                ushort4v u; u.x=f2u(v.x); u.y=f2u(v.y); u.z=f2u(v.z); u.w=f2u(v.w);
                *(ushort4v*)&As[r][kk] = u;
            }
        }
        {   // B tile: 64n x 32k, one pass
            int nn = t>>2, kk = (t&3)*8;
            *(ushort8*)&Bs[nn][kk] = *(const ushort8*)&Bt[(size_t)(col0+nn)*320 + k0+kk];
        }
        __syncthreads();
        bf16x8 a[4], b[2];
        #pragma unroll
        for(int mf=0;mf<4;mf++) a[mf] = *(const bf16x8*)&As[wm*64+mf*16+l15][lk*8];
        #pragma unroll
        for(int nf=0;nf<2;nf++) b[nf] = *(const bf16x8*)&Bs[wn*32+nf*16+l15][lk*8];
        #pragma unroll
        for(int mf=0;mf<4;mf++)
            #pragma unroll
            for(int nf=0;nf<2;nf++)
                acc[mf][nf] = __builtin_amdgcn_mfma_f32_16x16x32_bf16(a[mf], b[nf], acc[mf][nf], 0,0,0);
        __syncthreads();
    }
    // epilogue: D col=lane&15, row=4*(lane>>4)+reg
    if(C_F32){
        float* Cf = (float*)C;
        float bv[2];
        #pragma unroll
        for(int nf=0;nf<2;nf++) bv[nf] = bias[col0+wn*32+nf*16+l15];
        #pragma unroll
        for(int mf=0;mf<4;mf++)
            #pragma unroll
            for(int nf=0;nf<2;nf++){
                int col = col0+wn*32+nf*16+l15;
                #pragma unroll
                for(int r=0;r<4;r++){
                    int m = row0+wm*64+mf*16+lk*4+r;
                    Cf[(size_t)m*320+col] = acc[mf][nf][r] + bv[nf];
                }
            }
    } else {
        unsigned short* Cb = (unsigned short*)C;
        #pragma unroll
        for(int mf=0;mf<4;mf++)
            #pragma unroll
            for(int nf=0;nf<2;nf++){
                int col = col0+wn*32+nf*16+l15;
                #pragma unroll
                for(int r=0;r<4;r++){
                    int m = row0+wm*64+mf*16+lk*4+r;
                    Cb[(size_t)m*320+col] = f2u(acc[mf][nf][r]);
                }
            }
    }
}

// ---------------- global masked moments of sim (q bf16, k bf16)
__global__ __launch_bounds__(256) void stats_kernel(const unsigned short* __restrict__ qws,
                                                    const unsigned short* __restrict__ kws,
                                                    const int* __restrict__ ct, Stats* st){
    int bh = blockIdx.x;             // 0..63
    int n0 = blockIdx.y*256;
    int b  = bh>>3;
    __shared__ float kl[JJ*DIMH];
    __shared__ int kvalid[JJ];
    for(int i=threadIdx.x;i<JJ*DIMH;i+=256) kl[i]=u2f(kws[(size_t)bh*JJ*DIMH+i]);
    if(threadIdx.x<JJ) kvalid[threadIdx.x] = (ct[b*JJ+threadIdx.x]>=0)?1:0;
    __syncthreads();
    int n = n0 + threadIdx.x;
    int h = bh&7;
    const ushort8* qr8 = (const ushort8*)(qws + (size_t)(b*NN+n)*INNER + h*DIMH);
    float q[DIMH];
    #pragma unroll
    for(int i=0;i<5;i++){
        ushort8 u = qr8[i];
        #pragma unroll
        for(int jj=0;jj<8;jj++) q[i*8+jj] = u2f(u[jj]);
    }
    float s1=0.f, s2=0.f;
    for(int j=0;j<JJ;j++){
        float s=0.f;
        #pragma unroll
        for(int d4=0;d4<10;d4++){
            float4 k4 = *(const float4*)&kl[j*DIMH+d4*4];
            s += q[d4*4+0]*k4.x + q[d4*4+1]*k4.y + q[d4*4+2]*k4.z + q[d4*4+3]*k4.w;
        }
        if(kvalid[j]){ s1+=s; s2+=s*s; }
    }
    #pragma unroll
    for(int off=32;off>0;off>>=1){ s1 += __shfl_down(s1,off); s2 += __shfl_down(s2,off); }
    __shared__ float sa[4], sb[4];
    int lane = threadIdx.x&63, w = threadIdx.x>>6;
    if(lane==0){ sa[w]=s1; sb[w]=s2; }
    __syncthreads();
    if(threadIdx.x==0){
        double S1 = (double)sa[0]+sa[1]+sa[2]+sa[3];
        double S2 = (double)sb[0]+sb[1]+sb[2]+sb[3];
        atomicAdd(&st->s1, S1);
        atomicAdd(&st->s2, S2);
    }
}

__global__ void finalize_kernel(Stats* st){
    double cnt = (double)st->validcnt * HEADS * NN;
    double var = (st->s2 - st->s1*st->s1/cnt)/(cnt-1.0);
    st->simstd = (float)sqrt(var);
}

// ---------------- fused attention: online softmax, single QK^T pass
__global__ __launch_bounds__(256) void attn_kernel(const unsigned short* __restrict__ qws,
                                                   const unsigned short* __restrict__ kws,
                                                   const unsigned short* __restrict__ vws,
                                                   const float* __restrict__ cam,
                                                   const float* __restrict__ strength,
                                                   const int* __restrict__ ct,
                                                   const int* __restrict__ gpm,
                                                   const Stats* st,
                                                   unsigned short* __restrict__ ao){
    int bh = blockIdx.x; int n0 = blockIdx.y*256;
    int b = bh>>3, h = bh&7;
    __shared__ float kl[JJ*DIMH], vl[JJ*DIMH];
    __shared__ float kmul[JJ], addj[JJ], gmulc[JJ];
    for(int i=threadIdx.x;i<JJ*DIMH;i+=256){
        kl[i]=u2f(kws[(size_t)bh*JJ*DIMH+i]);
        vl[i]=u2f(vws[(size_t)bh*JJ*DIMH+i]);
    }
    if(threadIdx.x<JJ){
        int j=threadIdx.x;
        int kv = ct[b*JJ+j]>=0;
        int gv;
        if(st->gflag) gv = (((const unsigned char*)gpm)[b*JJ+j]!=0);
        else          gv = (gpm[b*JJ+j]!=0);
        float c = st->simstd * strength[0];
        kmul[j] = kv?1.f:0.f;
        addj[j] = (kv?0.f:NEGF) + (gv?0.f:NEGF);   // may overflow to -inf: handled
        gmulc[j]= gv? c : 0.f;
    }
    __syncthreads();
    int n = n0+threadIdx.x;
    const ushort8* qr8 = (const ushort8*)(qws + (size_t)(b*NN+n)*INNER + h*DIMH);
    float q[DIMH];
    #pragma unroll
    for(int i=0;i<5;i++){
        ushort8 u = qr8[i];
        #pragma unroll
        for(int jj=0;jj<8;jj++) q[i*8+jj] = u2f(u[jj]);
    }
    const float* camr = cam + (size_t)(b*NN+n)*JJ;
    const float scale = 0.15811388300841897f;
    float m = -1.0e30f;                // finite init: avoids inf-inf NaN
    float denom = 0.f;
    float o[DIMH];
    #pragma unroll
    for(int d=0;d<DIMH;d++) o[d]=0.f;
    for(int j=0;j<JJ;j++){
        float s=0.f;
        #pragma unroll
        for(int d4=0;d4<10;d4++){
            float4 k4 = *(const float4*)&kl[j*DIMH+d4*4];
            s += q[d4*4+0]*k4.x + q[d4*4+1]*k4.y + q[d4*4+2]*k4.z + q[d4*4+3]*k4.w;
        }
        float logit = (s*kmul[j] + camr[j]*gmulc[j] + addj[j])*scale;
        if(logit > m){
            float corr = __expf(m - logit);
            m = logit;
            denom *= corr;
            #pragma unroll
            for(int d=0;d<DIMH;d++) o[d] *= corr;
        }
        float p = __expf(logit - m);
        denom += p;
        #pragma unroll
        for(int d4=0;d4<10;d4++){
            float4 v4 = *(const float4*)&vl[j*DIMH+d4*4];
            o[d4*4+0] += p*v4.x; o[d4*4+1] += p*v4.y;
            o[d4*4+2] += p*v4.z; o[d4*4+3] += p*v4.w;
        }
    }
    float inv = 1.f/denom;
    ushort8* aor = (ushort8*)(ao + (size_t)(b*NN+n)*INNER + h*DIMH);
    #pragma unroll
    for(int i=0;i<5;i++){
        ushort8 u;
        #pragma unroll
        for(int jj=0;jj<8;jj++) u[jj] = f2u(o[i*8+jj]*inv);
        aor[i] = u;
    }
}

extern "C" void kernel_launch(void* const* d_in, const int* in_sizes, int n_in,
                              void* d_out, int out_size, void* d_ws, size_t ws_size,
                              hipStream_t stream) {
    const float* x        = (const float*)d_in[0];
    const float* embs     = (const float*)d_in[1];
    const float* Wq       = (const float*)d_in[2];
    const float* Wk       = (const float*)d_in[3];
    const float* Wv       = (const float*)d_in[4];
    const float* Wo       = (const float*)d_in[5];
    const float* bo       = (const float*)d_in[6];
    const float* cam      = (const float*)d_in[7];
    const float* strength = (const float*)d_in[8];
    const int*  ct       = (const int*)d_in[9];
    const int*  gpm      = (const int*)d_in[10];

    char* ws = (char*)d_ws;
    unsigned short* qws = (unsigned short*)ws;                    // 20,971,520 B
    unsigned short* ao  = (unsigned short*)(ws + 20971520);       // 20,971,520 B
    unsigned short* kws = (unsigned short*)(ws + 41943040);       // 394,240 B
    unsigned short* vws = (unsigned short*)(ws + 42337280);       // 394,240 B
    unsigned short* WqT = (unsigned short*)(ws + 42731520);       // 204,800 B
    unsigned short* WoT = (unsigned short*)(ws + 42936320);       // 204,800 B
    Stats* st  = (Stats*)(ws + 43141120);

    prep_kernel<<<1,256,0,stream>>>(ct,gpm,st);
    transpose_conv<<<100,256,0,stream>>>(Wq,WqT,320,320);
    transpose_conv<<<100,256,0,stream>>>(Wo,WoT,320,320);
    proj_kv<<<BB*JJ,256,0,stream>>>(embs,Wk,Wv,kws,vws);
    gemm_mfma<0,0><<<1280,256,0,stream>>>(x,WqT,nullptr,qws);
    stats_kernel<<<dim3(64,16),256,0,stream>>>(qws,kws,ct,st);
    finalize_kernel<<<1,1,0,stream>>>(st);
    attn_kernel<<<dim3(64,16),256,0,stream>>>(qws,kws,vws,cam,strength,ct,gpm,st,ao);
    gemm_mfma<1,1><<<1280,256,0,stream>>>(ao,WoT,bo,d_out);
}

// Round 5
// 256.115 us; speedup vs baseline: 2.9362x; 1.2997x over previous
//
#include <hip/hip_runtime.h>
#include <hip/hip_bf16.h>
#include <math.h>

#define HEADS 8
#define DIMH 40
#define BB 8
#define NN 4096
#define JJ 77
#define CDIM 768
#define INNER 320
#define NEGF (-3.4028234663852886e38f)

using bf16 = __hip_bfloat16;
using f32x4 = __attribute__((ext_vector_type(4))) float;
using bf16x8 = __attribute__((ext_vector_type(8))) short;
using ushort8 = __attribute__((ext_vector_type(8))) unsigned short;
using ushort4v = __attribute__((ext_vector_type(4))) unsigned short;

__device__ __forceinline__ unsigned short f2u(float f){
    bf16 t = __float2bfloat16(f);
    return *reinterpret_cast<unsigned short*>(&t);
}
__device__ __forceinline__ float u2f(unsigned short u){
    unsigned int w = ((unsigned int)u) << 16;
    return __uint_as_float(w);
}

struct Stats { double s1; double s2; int validcnt; int gflag; float simstd; };

// ---------------- prep
__global__ void prep_kernel(const int* ct, const int* gpm, Stats* st){
    __shared__ int sflag, scnt;
    if(threadIdx.x==0){ sflag=0; scnt=0; }
    __syncthreads();
    int lflag=0, lcnt=0;
    for(int i=threadIdx.x;i<154;i+=blockDim.x){
        int g = gpm[i];
        if(g!=0 && g!=1) lflag=1;
    }
    for(int i=threadIdx.x;i<BB*JJ;i+=blockDim.x){
        if(ct[i]>=0) lcnt++;
    }
    if(lflag) atomicOr(&sflag,1);
    atomicAdd(&scnt,lcnt);
    __syncthreads();
    if(threadIdx.x==0){ st->s1=0.0; st->s2=0.0; st->validcnt=scnt; st->gflag=sflag; }
}

// ---------------- flat fp32 -> bf16 convert (n multiple of 4)
__global__ __launch_bounds__(256) void conv_bf16(const float* __restrict__ in,
                                                 unsigned short* __restrict__ out, int n){
    int i = (blockIdx.x*256 + threadIdx.x)*4;
    if(i < n){
        float4 v = *(const float4*)&in[i];
        ushort4v u; u.x=f2u(v.x); u.y=f2u(v.y); u.z=f2u(v.z); u.w=f2u(v.w);
        *(ushort4v*)&out[i] = u;
    }
}

// ---------------- transpose + fp32->bf16: out[C][R] = in[R][C] (square multiples of 32)
__global__ __launch_bounds__(256) void transpose_conv(const float* __restrict__ in,
                                                      unsigned short* __restrict__ out,
                                                      int R, int C){
    __shared__ float tile[32][33];
    int nbx = C/32;
    int bx = blockIdx.x % nbx, by = blockIdx.x / nbx;
    int c0 = bx*32, r0 = by*32;
    int tx = threadIdx.x & 31, ty = threadIdx.x >> 5;
    #pragma unroll
    for(int i=0;i<32;i+=8) tile[ty+i][tx] = in[(size_t)(r0+ty+i)*C + c0+tx];
    __syncthreads();
    #pragma unroll
    for(int i=0;i<32;i+=8) out[(size_t)(c0+ty+i)*R + r0+tx] = f2u(tile[tx][ty+i]);
}

// ---------------- cam transpose: cam[b][n][j] fp32 -> camT[b][j][n] bf16
__global__ __launch_bounds__(256) void cam_transpose(const float* __restrict__ cam,
                                                     unsigned short* __restrict__ camT){
    __shared__ float tile[64][81];   // 81: odd stride -> 2-way banks only
    int b  = blockIdx.x >> 6;
    int n0 = (blockIdx.x & 63)*64;
    const float* src = cam + ((size_t)b*NN + n0)*JJ;
    for(int idx=threadIdx.x; idx<64*JJ; idx+=256){
        int r = idx/JJ, c = idx - r*JJ;
        tile[r][c] = src[idx];
    }
    __syncthreads();
    for(int idx=threadIdx.x; idx<JJ*64; idx+=256){
        int j = idx>>6, n = idx&63;
        camT[((size_t)b*JJ + j)*NN + n0 + n] = f2u(tile[n][j]);
    }
}

// ---------------- k,v projection: 4 (b,j) rows per block, 320 threads
__global__ __launch_bounds__(320) void proj_kv(const float* __restrict__ embs,
                                               const unsigned short* __restrict__ Wkb,
                                               const unsigned short* __restrict__ Wvb,
                                               unsigned short* __restrict__ kws,
                                               unsigned short* __restrict__ vws){
    int bj0 = blockIdx.x*4;          // 154 blocks * 4 = 616
    __shared__ float e4[4][CDIM];
    const float* src = embs + (size_t)bj0*CDIM;
    for(int i=threadIdx.x;i<4*CDIM;i+=320) ((float*)e4)[i] = src[i];
    __syncthreads();
    int col = threadIdx.x;           // 0..319: one Wk col + one Wv col
    float ak[4]={0.f,0.f,0.f,0.f}, av[4]={0.f,0.f,0.f,0.f};
    for(int c=0;c<CDIM;c++){
        float wk = u2f(Wkb[c*INNER+col]);
        float wv = u2f(Wvb[c*INNER+col]);
        #pragma unroll
        for(int r=0;r<4;r++){ float ev=e4[r][c]; ak[r]+=ev*wk; av[r]+=ev*wv; }
    }
    int h = col/DIMH, d = col-h*DIMH;
    #pragma unroll
    for(int r=0;r<4;r++){
        int bj = bj0+r; int b = bj/JJ; int j = bj-b*JJ;
        size_t o = (((size_t)b*HEADS+h)*JJ + j)*DIMH + d;
        kws[o] = f2u(ak[r]);
        vws[o] = f2u(av[r]);
    }
}

// ---------------- MFMA GEMM: C[M][320] = A[M][320] * B[320][320] (+bias)
template<int A_BF16, int C_F32>
__global__ __launch_bounds__(256) void gemm_mfma(const void* __restrict__ A,
                                                 const unsigned short* __restrict__ Bt,
                                                 const float* __restrict__ bias,
                                                 void* __restrict__ C){
    __shared__ unsigned short As[128][40];
    __shared__ unsigned short Bs[64][40];
    int t = threadIdx.x;
    int bm = blockIdx.x & 255;
    int bn = blockIdx.x >> 8;
    int row0 = bm*128, col0 = bn*64;
    int wave = t>>6, lane = t&63;
    int wm = wave>>1, wn = wave&1;
    int l15 = lane&15, lk = lane>>4;

    f32x4 acc[4][2];
    #pragma unroll
    for(int i=0;i<4;i++)
        #pragma unroll
        for(int j=0;j<2;j++) acc[i][j] = (f32x4){0.f,0.f,0.f,0.f};

    for(int k0=0;k0<320;k0+=32){
        if(A_BF16){
            const unsigned short* Ab = (const unsigned short*)A;
            #pragma unroll
            for(int p=0;p<2;p++){
                int li = (p*256+t)*8; int r = li>>5, kk = li&31;
                *(ushort8*)&As[r][kk] = *(const ushort8*)&Ab[(size_t)(row0+r)*320 + k0+kk];
            }
        } else {
            const float* Af = (const float*)A;
            #pragma unroll
            for(int p=0;p<4;p++){
                int li = (p*256+t)*4; int r = li>>5, kk = li&31;
                float4 v = *(const float4*)&Af[(size_t)(row0+r)*320 + k0+kk];
                ushort4v u; u.x=f2u(v.x); u.y=f2u(v.y); u.z=f2u(v.z); u.w=f2u(v.w);
                *(ushort4v*)&As[r][kk] = u;
            }
        }
        {
            int nn = t>>2, kk = (t&3)*8;
            *(ushort8*)&Bs[nn][kk] = *(const ushort8*)&Bt[(size_t)(col0+nn)*320 + k0+kk];
        }
        __syncthreads();
        bf16x8 a[4], b[2];
        #pragma unroll
        for(int mf=0;mf<4;mf++) a[mf] = *(const bf16x8*)&As[wm*64+mf*16+l15][lk*8];
        #pragma unroll
        for(int nf=0;nf<2;nf++) b[nf] = *(const bf16x8*)&Bs[wn*32+nf*16+l15][lk*8];
        #pragma unroll
        for(int mf=0;mf<4;mf++)
            #pragma unroll
            for(int nf=0;nf<2;nf++)
                acc[mf][nf] = __builtin_amdgcn_mfma_f32_16x16x32_bf16(a[mf], b[nf], acc[mf][nf], 0,0,0);
        __syncthreads();
    }
    if(C_F32){
        float* Cf = (float*)C;
        float bv[2];
        #pragma unroll
        for(int nf=0;nf<2;nf++) bv[nf] = bias[col0+wn*32+nf*16+l15];
        #pragma unroll
        for(int mf=0;mf<4;mf++)
            #pragma unroll
            for(int nf=0;nf<2;nf++){
                int col = col0+wn*32+nf*16+l15;
                #pragma unroll
                for(int r=0;r<4;r++){
                    int m = row0+wm*64+mf*16+lk*4+r;
                    Cf[(size_t)m*320+col] = acc[mf][nf][r] + bv[nf];
                }
            }
    } else {
        unsigned short* Cb = (unsigned short*)C;
        #pragma unroll
        for(int mf=0;mf<4;mf++)
            #pragma unroll
            for(int nf=0;nf<2;nf++){
                int col = col0+wn*32+nf*16+l15;
                #pragma unroll
                for(int r=0;r<4;r++){
                    int m = row0+wm*64+mf*16+lk*4+r;
                    Cb[(size_t)m*320+col] = f2u(acc[mf][nf][r]);
                }
            }
    }
}

// ---------------- global masked moments of sim
__global__ __launch_bounds__(256) void stats_kernel(const unsigned short* __restrict__ qws,
                                                    const unsigned short* __restrict__ kws,
                                                    const int* __restrict__ ct, Stats* st){
    int bh = blockIdx.x;
    int n0 = blockIdx.y*256;
    int b  = bh>>3;
    __shared__ float kl[JJ*DIMH];
    __shared__ int kvalid[JJ];
    for(int i=threadIdx.x;i<JJ*DIMH;i+=256) kl[i]=u2f(kws[(size_t)bh*JJ*DIMH+i]);
    if(threadIdx.x<JJ) kvalid[threadIdx.x] = (ct[b*JJ+threadIdx.x]>=0)?1:0;
    __syncthreads();
    int n = n0 + threadIdx.x;
    int h = bh&7;
    const ushort8* qr8 = (const ushort8*)(qws + (size_t)(b*NN+n)*INNER + h*DIMH);
    float q[DIMH];
    #pragma unroll
    for(int i=0;i<5;i++){
        ushort8 u = qr8[i];
        #pragma unroll
        for(int jj=0;jj<8;jj++) q[i*8+jj] = u2f(u[jj]);
    }
    float s1=0.f, s2=0.f;
    for(int j=0;j<JJ;j++){
        float s=0.f;
        #pragma unroll
        for(int d4=0;d4<10;d4++){
            float4 k4 = *(const float4*)&kl[j*DIMH+d4*4];
            s += q[d4*4+0]*k4.x + q[d4*4+1]*k4.y + q[d4*4+2]*k4.z + q[d4*4+3]*k4.w;
        }
        if(kvalid[j]){ s1+=s; s2+=s*s; }
    }
    #pragma unroll
    for(int off=32;off>0;off>>=1){ s1 += __shfl_down(s1,off); s2 += __shfl_down(s2,off); }
    __shared__ float sa[4], sb[4];
    int lane = threadIdx.x&63, w = threadIdx.x>>6;
    if(lane==0){ sa[w]=s1; sb[w]=s2; }
    __syncthreads();
    if(threadIdx.x==0){
        double S1 = (double)sa[0]+sa[1]+sa[2]+sa[3];
        double S2 = (double)sb[0]+sb[1]+sb[2]+sb[3];
        atomicAdd(&st->s1, S1);
        atomicAdd(&st->s2, S2);
    }
}

__global__ void finalize_kernel(Stats* st){
    double cnt = (double)st->validcnt * HEADS * NN;
    double var = (st->s2 - st->s1*st->s1/cnt)/(cnt-1.0);
    st->simstd = (float)sqrt(var);
}

// ---------------- fused attention: online softmax; output IN-PLACE into qws
__global__ __launch_bounds__(256) void attn_kernel(unsigned short* qws,   // q in, out in-place
                                                   const unsigned short* __restrict__ kws,
                                                   const unsigned short* __restrict__ vws,
                                                   const unsigned short* __restrict__ camT,
                                                   const float* __restrict__ strength,
                                                   const int* __restrict__ ct,
                                                   const int* __restrict__ gpm,
                                                   const Stats* st){
    int bh = blockIdx.x; int n0 = blockIdx.y*256;
    int b = bh>>3, h = bh&7;
    __shared__ float kl[JJ*DIMH], vl[JJ*DIMH];
    __shared__ float kmul[JJ], addj[JJ], gmulc[JJ];
    for(int i=threadIdx.x;i<JJ*DIMH;i+=256){
        kl[i]=u2f(kws[(size_t)bh*JJ*DIMH+i]);
        vl[i]=u2f(vws[(size_t)bh*JJ*DIMH+i]);
    }
    if(threadIdx.x<JJ){
        int j=threadIdx.x;
        int kv = ct[b*JJ+j]>=0;
        int gv;
        if(st->gflag) gv = (((const unsigned char*)gpm)[b*JJ+j]!=0);
        else          gv = (gpm[b*JJ+j]!=0);
        float c = st->simstd * strength[0];
        kmul[j] = kv?1.f:0.f;
        addj[j] = (kv?0.f:NEGF) + (gv?0.f:NEGF);
        gmulc[j]= gv? c : 0.f;
    }
    __syncthreads();
    int n = n0+threadIdx.x;
    ushort8* qr8 = (ushort8*)(qws + (size_t)(b*NN+n)*INNER + h*DIMH);
    float q[DIMH];
    #pragma unroll
    for(int i=0;i<5;i++){
        ushort8 u = qr8[i];
        #pragma unroll
        for(int jj=0;jj<8;jj++) q[i*8+jj] = u2f(u[jj]);
    }
    const unsigned short* camp = camT + (size_t)b*JJ*NN + n;
    const float scale = 0.15811388300841897f;
    float m = -1.0e30f;
    float denom = 0.f;
    float o[DIMH];
    #pragma unroll
    for(int d=0;d<DIMH;d++) o[d]=0.f;
    for(int j=0;j<JJ;j++){
        float s=0.f;
        #pragma unroll
        for(int d4=0;d4<10;d4++){
            float4 k4 = *(const float4*)&kl[j*DIMH+d4*4];
            s += q[d4*4+0]*k4.x + q[d4*4+1]*k4.y + q[d4*4+2]*k4.z + q[d4*4+3]*k4.w;
        }
        float cv = u2f(camp[(size_t)j*NN]);
        float logit = (s*kmul[j] + cv*gmulc[j] + addj[j])*scale;
        if(logit > m){
            float corr = __expf(m - logit);
            m = logit;
            denom *= corr;
            #pragma unroll
            for(int d=0;d<DIMH;d++) o[d] *= corr;
        }
        float p = __expf(logit - m);
        denom += p;
        #pragma unroll
        for(int d4=0;d4<10;d4++){
            float4 v4 = *(const float4*)&vl[j*DIMH+d4*4];
            o[d4*4+0] += p*v4.x; o[d4*4+1] += p*v4.y;
            o[d4*4+2] += p*v4.z; o[d4*4+3] += p*v4.w;
        }
    }
    float inv = 1.f/denom;
    #pragma unroll
    for(int i=0;i<5;i++){
        ushort8 u;
        #pragma unroll
        for(int jj=0;jj<8;jj++) u[jj] = f2u(o[i*8+jj]*inv);
        qr8[i] = u;
    }
}

extern "C" void kernel_launch(void* const* d_in, const int* in_sizes, int n_in,
                              void* d_out, int out_size, void* d_ws, size_t ws_size,
                              hipStream_t stream) {
    const float* x        = (const float*)d_in[0];
    const float* embs     = (const float*)d_in[1];
    const float* Wq       = (const float*)d_in[2];
    const float* Wk       = (const float*)d_in[3];
    const float* Wv       = (const float*)d_in[4];
    const float* Wo       = (const float*)d_in[5];
    const float* bo       = (const float*)d_in[6];
    const float* cam      = (const float*)d_in[7];
    const float* strength = (const float*)d_in[8];
    const int*  ct       = (const int*)d_in[9];
    const int*  gpm      = (const int*)d_in[10];

    char* ws = (char*)d_ws;
    unsigned short* qws = (unsigned short*)ws;                    // 20,971,520 B (q, then attn out in-place)
    unsigned short* kws = (unsigned short*)(ws + 20971520);       // 394,240
    unsigned short* vws = (unsigned short*)(ws + 21365760);       // 394,240
    unsigned short* WqT = (unsigned short*)(ws + 21760000);       // 204,800
    unsigned short* WoT = (unsigned short*)(ws + 21964800);       // 204,800
    unsigned short* Wkb = (unsigned short*)(ws + 22169600);       // 491,520
    unsigned short* Wvb = (unsigned short*)(ws + 22661120);       // 491,520
    unsigned short* camT= (unsigned short*)(ws + 23152640);       // 5,046,272
    Stats* st  = (Stats*)(ws + 28198912);

    prep_kernel<<<1,256,0,stream>>>(ct,gpm,st);
    conv_bf16<<<240,256,0,stream>>>(Wk,Wkb,CDIM*INNER);
    conv_bf16<<<240,256,0,stream>>>(Wv,Wvb,CDIM*INNER);
    transpose_conv<<<100,256,0,stream>>>(Wq,WqT,320,320);
    transpose_conv<<<100,256,0,stream>>>(Wo,WoT,320,320);
    cam_transpose<<<512,256,0,stream>>>(cam,camT);
    proj_kv<<<154,320,0,stream>>>(embs,Wkb,Wvb,kws,vws);
    gemm_mfma<0,0><<<1280,256,0,stream>>>(x,WqT,nullptr,qws);
    stats_kernel<<<dim3(64,16),256,0,stream>>>(qws,kws,ct,st);
    finalize_kernel<<<1,1,0,stream>>>(st);
    attn_kernel<<<dim3(64,16),256,0,stream>>>(qws,kws,vws,camT,strength,ct,gpm,st);
    gemm_mfma<1,1><<<1280,256,0,stream>>>(qws,WoT,bo,d_out);
}